// Round 4
// baseline (179.352 us; speedup 1.0000x reference)
//
#include <hip/hip_runtime.h>

#define NN 1024
#define NP (NN * NN)

// ---------------- k1: LayerNorm + GEMV, decoupled-reduction form ------------
// x_d = rstd*(g_d - mu*A_d) + B_d + b_d
//   g_d = sum_c x_c * (gamma_c*W_cd)   (per-pair, reduced with s,q in ONE pass)
//   A_d = sum_c gamma_c*W_cd, B_d = sum_c beta_c*W_cd   (loop-invariant)
// 16 lanes/pair, 8 ch/lane; explicit 2-deep load prefetch.
__global__ __launch_bounds__(256) void k_ln_gemv(
    const float* __restrict__ pairp, const float* __restrict__ gamma,
    const float* __restrict__ beta, const float* __restrict__ W,
    const float* __restrict__ bvec, float* __restrict__ xout, int ngroups)
{
  const int l = threadIdx.x & 15;
  const int group = blockIdx.x * 16 + (threadIdx.x >> 4);

  float ug[8][6], apart[6] = {0, 0, 0, 0, 0, 0}, bpart[6] = {0, 0, 0, 0, 0, 0};
#pragma unroll
  for (int k = 0; k < 2; ++k)
#pragma unroll
    for (int m = 0; m < 4; ++m) {
      const int c = 4 * l + 64 * k + m;
      const int idx = 4 * k + m;
      const float ga = gamma[c], be = beta[c];
#pragma unroll
      for (int d = 0; d < 6; ++d) {
        const float w = W[c * 6 + d];
        ug[idx][d] = ga * w;
        apart[d] += ga * w;
        bpart[d] += be * w;
      }
    }
#pragma unroll
  for (int d = 0; d < 6; ++d)
#pragma unroll
    for (int m = 1; m <= 8; m <<= 1) {
      apart[d] += __shfl_xor(apart[d], m);
      bpart[d] += __shfl_xor(bpart[d], m);
    }
  const float vA = (l == 0) ? apart[0] : (l == 1) ? apart[1] : (l == 2) ? apart[2]
                  : (l == 3) ? apart[3] : (l == 4) ? apart[4] : apart[5];
  float vB = (l == 0) ? bpart[0] : (l == 1) ? bpart[1] : (l == 2) ? bpart[2]
            : (l == 3) ? bpart[3] : (l == 4) ? bpart[4] : bpart[5];
  if (l < 6) vB += bvec[l];

  size_t p = (size_t)group;
  {
    const float* base = pairp + p * 128 + 4 * l;
    float4 na = *(const float4*)(base);
    float4 nb = *(const float4*)(base + 64);
    while (p < NP) {
      const float4 xa = na, xb = nb;
      const size_t p2 = p + (size_t)ngroups;
      if (p2 < NP) {  // prefetch next iteration before the compute chain
        const float* nbase = pairp + p2 * 128 + 4 * l;
        na = *(const float4*)(nbase);
        nb = *(const float4*)(nbase + 64);
      }
      const float xv[8] = {xa.x, xa.y, xa.z, xa.w, xb.x, xb.y, xb.z, xb.w};
      float s = 0.f, q = 0.f, g[6] = {0, 0, 0, 0, 0, 0};
#pragma unroll
      for (int k = 0; k < 8; ++k) {
        s += xv[k];
        q = fmaf(xv[k], xv[k], q);
#pragma unroll
        for (int d = 0; d < 6; ++d) g[d] = fmaf(xv[k], ug[k][d], g[d]);
      }
      // one combined butterfly: 8 independent chains of depth 4
#pragma unroll
      for (int m = 1; m <= 8; m <<= 1) {
        s += __shfl_xor(s, m);
        q += __shfl_xor(q, m);
#pragma unroll
        for (int d = 0; d < 6; ++d) g[d] += __shfl_xor(g[d], m);
      }
      if (l < 6) {
        const float mu = s * (1.f / 128.f);
        const float var = q * (1.f / 128.f) - mu * mu;
        const float rstd = rsqrtf(var + 1e-5f);
        const float vg = (l == 0) ? g[0] : (l == 1) ? g[1] : (l == 2) ? g[2]
                        : (l == 3) ? g[3] : (l == 4) ? g[4] : g[5];
        xout[p * 6 + l] = fmaf(rstd, vg - mu * vA, vB);
      }
      p = p2;
    }
  }
}

// ---------------- k_sym: one-shot tiled symmetrize + mask + rowsum -----------
__global__ __launch_bounds__(256) void k_sym(
    const float* __restrict__ x, const int* __restrict__ seq,
    float* __restrict__ xs, float* __restrict__ rowsum)
{
  const int J = blockIdx.x, I = blockIdx.y;
  const int tid = threadIdx.x;
  __shared__ float M[32 * 193];

  const float* mb = x + ((size_t)(J * 32) * NN + I * 32) * 6;
  for (int k = tid; k < 1536; k += 256) {
    const int m = k / 48, f = k % 48;
    const float4 v = *(const float4*)(mb + (size_t)m * (NN * 6) + f * 4);
    float* dst = &M[m * 193 + f * 4];
    dst[0] = v.x; dst[1] = v.y; dst[2] = v.z; dst[3] = v.w;
  }
  __syncthreads();

  float es[4][6];
#pragma unroll
  for (int q = 0; q < 4; ++q) {
    const int e = tid + 256 * q;
    const int r = e >> 5, c = e & 31;
    const int i = I * 32 + r, j = J * 32 + c;
    const int dd = seq[i] - seq[j];
    const bool far = (dd > 3) || (dd < -3);
    const float* own = x + ((size_t)i * NN + j) * 6;
    const float2 o0 = *(const float2*)(own);
    const float2 o1 = *(const float2*)(own + 2);
    const float2 o2 = *(const float2*)(own + 4);
    const float* mr = &M[c * 193 + r * 6];
    float v[6];
    v[0] = far ? 0.5f * (o0.x + mr[0]) : -1000000.f;
    v[1] = far ? 0.5f * (o0.y + mr[1]) : -1000000.f;
    v[2] = far ? 0.5f * (o1.x + mr[2]) : -1000000.f;
    v[3] = far ? 0.5f * (o1.y + mr[3]) : -1000000.f;
    v[4] = far ? 0.5f * (o2.x + mr[4]) : -1000000.f;
    v[5] = far ? 0.5f * (o2.y + mr[5]) : -1000000.f;
    float* op = xs + ((size_t)i * NN + j) * 6;
    *(float2*)(op) = make_float2(v[0], v[1]);
    *(float2*)(op + 2) = make_float2(v[2], v[3]);
    *(float2*)(op + 4) = make_float2(v[4], v[5]);
#pragma unroll
    for (int d = 0; d < 6; ++d) es[q][d] = __expf(v[d]);
  }

#pragma unroll
  for (int q = 0; q < 4; ++q)
#pragma unroll
    for (int d = 0; d < 6; ++d)
#pragma unroll
      for (int m = 1; m <= 16; m <<= 1) es[q][d] += __shfl_xor(es[q][d], m);

  if ((tid & 31) == 0) {
    const int w = tid >> 5;
#pragma unroll
    for (int q = 0; q < 4; ++q) {
      const int i = I * 32 + w + 8 * q;
#pragma unroll
      for (int d = 0; d < 6; ++d) atomicAdd(&rowsum[i * 6 + d], es[q][d]);
    }
  }
}

__global__ __launch_bounds__(256) void k_lse(
    const float* __restrict__ rowsum, float* __restrict__ lse)
{
  const int k = blockIdx.x * 256 + threadIdx.x;
  if (k < NN * 6) lse[k] = logf(1.0f + rowsum[k]);
}

__global__ __launch_bounds__(256) void k_out(
    float* __restrict__ out, const float* __restrict__ lse)
{
  const int p = blockIdx.x * 256 + threadIdx.x;
  const int i = p >> 10;
  const int j = p & (NN - 1);

  float* a = out + (size_t)p * 6;
  const float2 a0 = *(const float2*)(a);
  const float2 a1 = *(const float2*)(a + 2);
  const float2 a2 = *(const float2*)(a + 4);
  const float v[6] = {a0.x, a0.y, a1.x, a1.y, a2.x, a2.y};

  float ssum = 0.f;
#pragma unroll
  for (int d = 0; d < 6; ++d) ssum += __expf(v[d]);
  const float lc2 = 2.f * logf(1.f + ssum);

  const float* li = lse + i * 6;
  const float* lj = lse + j * 6;
  float o[6];
#pragma unroll
  for (int d = 0; d < 6; ++d) o[d] = 4.f * v[d] - li[d] - lj[d] - lc2;

  *(float2*)(a) = make_float2(o[0], o[1]);
  *(float2*)(a + 2) = make_float2(o[2], o[3]);
  *(float2*)(a + 4) = make_float2(o[4], o[5]);
}

extern "C" void kernel_launch(void* const* d_in, const int* in_sizes, int n_in,
                              void* d_out, int out_size, void* d_ws, size_t ws_size,
                              hipStream_t stream) {
  const float* pairp = (const float*)d_in[0];
  const int* seq = (const int*)d_in[1];
  const float* gamma = (const float*)d_in[2];
  const float* beta = (const float*)d_in[3];
  const float* W = (const float*)d_in[4];
  const float* bvec = (const float*)d_in[5];
  float* out = (float*)d_out;

  float* x = (float*)d_ws;              // raw x: 1024*1024*6 fp32 = 24 MB
  float* rowsum = x + (size_t)NP * 6;   // 1024*6
  float* lse = rowsum + NN * 6;         // 1024*6

  hipMemsetAsync(rowsum, 0, NN * 6 * sizeof(float), stream);
  k_ln_gemv<<<2048, 256, 0, stream>>>(pairp, gamma, beta, W, bvec, x, 2048 * 16);
  k_sym<<<dim3(32, 32), 256, 0, stream>>>(x, seq, out, rowsum);  // xs -> out
  k_lse<<<(NN * 6 + 255) / 256, 256, 0, stream>>>(rowsum, lse);
  k_out<<<NP / 256, 256, 0, stream>>>(out, lse);
}

// Round 5
// 157.891 us; speedup vs baseline: 1.1359x; 1.1359x over previous
//
#include <hip/hip_runtime.h>

#define NN 1024
#define NP (NN * NN)
#define NBLK 1024
#define NGRP (NBLK * 16)   // 16384 groups, 2 pairs/group/iter -> 32 iters

typedef float f32x4 __attribute__((ext_vector_type(4)));

__device__ __forceinline__ f32x4 ntld(const float* p) {
  return __builtin_nontemporal_load((const f32x4*)p);
}

// ---------------- k1: LayerNorm + GEMV, decoupled form, persistent grid -----
// x_d = rstd*(g_d - mu*A_d) + B_d;  A_d = sum gamma*W, B_d = sum beta*W + b.
// 16 lanes/pair, 8 ch/lane; 2 pairs per group per iter; prefetch next iter.
__global__ __launch_bounds__(256) void k_ln_gemv(
    const float* __restrict__ pairp, const float* __restrict__ gamma,
    const float* __restrict__ beta, const float* __restrict__ W,
    const float* __restrict__ bvec, float* __restrict__ xout)
{
  const int l = threadIdx.x & 15;
  const int group = blockIdx.x * 16 + (threadIdx.x >> 4);

  float ug[8][6], apart[6] = {0, 0, 0, 0, 0, 0}, bpart[6] = {0, 0, 0, 0, 0, 0};
#pragma unroll
  for (int k = 0; k < 2; ++k)
#pragma unroll
    for (int m = 0; m < 4; ++m) {
      const int c = 4 * l + 64 * k + m;
      const int idx = 4 * k + m;
      const float ga = gamma[c], be = beta[c];
#pragma unroll
      for (int d = 0; d < 6; ++d) {
        const float w = W[c * 6 + d];
        ug[idx][d] = ga * w;
        apart[d] += ga * w;
        bpart[d] += be * w;
      }
    }
#pragma unroll
  for (int d = 0; d < 6; ++d)
#pragma unroll
    for (int m = 1; m <= 8; m <<= 1) {
      apart[d] += __shfl_xor(apart[d], m);
      bpart[d] += __shfl_xor(bpart[d], m);
    }
  const float vA = (l == 0) ? apart[0] : (l == 1) ? apart[1] : (l == 2) ? apart[2]
                  : (l == 3) ? apart[3] : (l == 4) ? apart[4] : apart[5];
  float vB = (l == 0) ? bpart[0] : (l == 1) ? bpart[1] : (l == 2) ? bpart[2]
            : (l == 3) ? bpart[3] : (l == 4) ? bpart[4] : bpart[5];
  if (l < 6) vB += bvec[l];

  size_t p = 2 * (size_t)group;
  const float* bp = pairp + p * 128 + 4 * l;
  f32x4 a0 = ntld(bp), b0 = ntld(bp + 64);
  f32x4 a1 = ntld(bp + 128), b1 = ntld(bp + 192);

  for (int it = 0; it < 32; ++it) {
    const size_t pn = p + 2 * NGRP;
    f32x4 na0, nb0, na1, nb1;
    if (it != 31) {  // prefetch next iteration's 4 loads before compute
      const float* nbp = pairp + pn * 128 + 4 * l;
      na0 = ntld(nbp); nb0 = ntld(nbp + 64);
      na1 = ntld(nbp + 128); nb1 = ntld(nbp + 192);
    }

    const float xv0[8] = {a0.x, a0.y, a0.z, a0.w, b0.x, b0.y, b0.z, b0.w};
    const float xv1[8] = {a1.x, a1.y, a1.z, a1.w, b1.x, b1.y, b1.z, b1.w};
    float r[16];
#pragma unroll
    for (int k = 0; k < 16; ++k) r[k] = 0.f;
#pragma unroll
    for (int k = 0; k < 8; ++k) {
      r[0] += xv0[k];
      r[1] = fmaf(xv0[k], xv0[k], r[1]);
      r[8] += xv1[k];
      r[9] = fmaf(xv1[k], xv1[k], r[9]);
#pragma unroll
      for (int d = 0; d < 6; ++d) {
        r[2 + d] = fmaf(xv0[k], ug[k][d], r[2 + d]);
        r[10 + d] = fmaf(xv1[k], ug[k][d], r[10 + d]);
      }
    }
    // one combined butterfly: 16 independent chains of depth 4
#pragma unroll
    for (int m = 1; m <= 8; m <<= 1)
#pragma unroll
      for (int k = 0; k < 16; ++k) r[k] += __shfl_xor(r[k], m);

    if (l < 6) {
      const float mu0 = r[0] * (1.f / 128.f);
      const float var0 = r[1] * (1.f / 128.f) - mu0 * mu0;
      const float rstd0 = rsqrtf(var0 + 1e-5f);
      const float vg0 = (l == 0) ? r[2] : (l == 1) ? r[3] : (l == 2) ? r[4]
                       : (l == 3) ? r[5] : (l == 4) ? r[6] : r[7];
      xout[p * 6 + l] = fmaf(rstd0, vg0 - mu0 * vA, vB);

      const float mu1 = r[8] * (1.f / 128.f);
      const float var1 = r[9] * (1.f / 128.f) - mu1 * mu1;
      const float rstd1 = rsqrtf(var1 + 1e-5f);
      const float vg1 = (l == 0) ? r[10] : (l == 1) ? r[11] : (l == 2) ? r[12]
                       : (l == 3) ? r[13] : (l == 4) ? r[14] : r[15];
      xout[(p + 1) * 6 + l] = fmaf(rstd1, vg1 - mu1 * vA, vB);
    }
    p = pn;
    a0 = na0; b0 = nb0; a1 = na1; b1 = nb1;
  }
}

// ---------------- k_sym: one-shot tiled symmetrize + mask + rowsum -----------
__global__ __launch_bounds__(256) void k_sym(
    const float* __restrict__ x, const int* __restrict__ seq,
    float* __restrict__ xs, float* __restrict__ rowsum)
{
  const int J = blockIdx.x, I = blockIdx.y;
  const int tid = threadIdx.x;
  __shared__ float M[32 * 193];

  const float* mb = x + ((size_t)(J * 32) * NN + I * 32) * 6;
  for (int k = tid; k < 1536; k += 256) {
    const int m = k / 48, f = k % 48;
    const float4 v = *(const float4*)(mb + (size_t)m * (NN * 6) + f * 4);
    float* dst = &M[m * 193 + f * 4];
    dst[0] = v.x; dst[1] = v.y; dst[2] = v.z; dst[3] = v.w;
  }
  __syncthreads();

  float es[4][6];
#pragma unroll
  for (int q = 0; q < 4; ++q) {
    const int e = tid + 256 * q;
    const int r = e >> 5, c = e & 31;
    const int i = I * 32 + r, j = J * 32 + c;
    const int dd = seq[i] - seq[j];
    const bool far = (dd > 3) || (dd < -3);
    const float* own = x + ((size_t)i * NN + j) * 6;
    const float2 o0 = *(const float2*)(own);
    const float2 o1 = *(const float2*)(own + 2);
    const float2 o2 = *(const float2*)(own + 4);
    const float* mr = &M[c * 193 + r * 6];
    float v[6];
    v[0] = far ? 0.5f * (o0.x + mr[0]) : -1000000.f;
    v[1] = far ? 0.5f * (o0.y + mr[1]) : -1000000.f;
    v[2] = far ? 0.5f * (o1.x + mr[2]) : -1000000.f;
    v[3] = far ? 0.5f * (o1.y + mr[3]) : -1000000.f;
    v[4] = far ? 0.5f * (o2.x + mr[4]) : -1000000.f;
    v[5] = far ? 0.5f * (o2.y + mr[5]) : -1000000.f;
    float* op = xs + ((size_t)i * NN + j) * 6;
    *(float2*)(op) = make_float2(v[0], v[1]);
    *(float2*)(op + 2) = make_float2(v[2], v[3]);
    *(float2*)(op + 4) = make_float2(v[4], v[5]);
#pragma unroll
    for (int d = 0; d < 6; ++d) es[q][d] = __expf(v[d]);
  }

#pragma unroll
  for (int q = 0; q < 4; ++q)
#pragma unroll
    for (int d = 0; d < 6; ++d)
#pragma unroll
      for (int m = 1; m <= 16; m <<= 1) es[q][d] += __shfl_xor(es[q][d], m);

  if ((tid & 31) == 0) {
    const int w = tid >> 5;
#pragma unroll
    for (int q = 0; q < 4; ++q) {
      const int i = I * 32 + w + 8 * q;
#pragma unroll
      for (int d = 0; d < 6; ++d) atomicAdd(&rowsum[i * 6 + d], es[q][d]);
    }
  }
}

__global__ __launch_bounds__(256) void k_lse(
    const float* __restrict__ rowsum, float* __restrict__ lse)
{
  const int k = blockIdx.x * 256 + threadIdx.x;
  if (k < NN * 6) lse[k] = logf(1.0f + rowsum[k]);
}

__global__ __launch_bounds__(256) void k_out(
    float* __restrict__ out, const float* __restrict__ lse)
{
  const int p = blockIdx.x * 256 + threadIdx.x;
  const int i = p >> 10;
  const int j = p & (NN - 1);

  float* a = out + (size_t)p * 6;
  const float2 a0 = *(const float2*)(a);
  const float2 a1 = *(const float2*)(a + 2);
  const float2 a2 = *(const float2*)(a + 4);
  const float v[6] = {a0.x, a0.y, a1.x, a1.y, a2.x, a2.y};

  float ssum = 0.f;
#pragma unroll
  for (int d = 0; d < 6; ++d) ssum += __expf(v[d]);
  const float lc2 = 2.f * logf(1.f + ssum);

  const float* li = lse + i * 6;
  const float* lj = lse + j * 6;
  float o[6];
#pragma unroll
  for (int d = 0; d < 6; ++d) o[d] = 4.f * v[d] - li[d] - lj[d] - lc2;

  *(float2*)(a) = make_float2(o[0], o[1]);
  *(float2*)(a + 2) = make_float2(o[2], o[3]);
  *(float2*)(a + 4) = make_float2(o[4], o[5]);
}

extern "C" void kernel_launch(void* const* d_in, const int* in_sizes, int n_in,
                              void* d_out, int out_size, void* d_ws, size_t ws_size,
                              hipStream_t stream) {
  const float* pairp = (const float*)d_in[0];
  const int* seq = (const int*)d_in[1];
  const float* gamma = (const float*)d_in[2];
  const float* beta = (const float*)d_in[3];
  const float* W = (const float*)d_in[4];
  const float* bvec = (const float*)d_in[5];
  float* out = (float*)d_out;

  float* x = (float*)d_ws;              // raw x: 1024*1024*6 fp32 = 24 MB
  float* rowsum = x + (size_t)NP * 6;   // 1024*6
  float* lse = rowsum + NN * 6;         // 1024*6

  hipMemsetAsync(rowsum, 0, NN * 6 * sizeof(float), stream);
  k_ln_gemv<<<NBLK, 256, 0, stream>>>(pairp, gamma, beta, W, bvec, x);
  k_sym<<<dim3(32, 32), 256, 0, stream>>>(x, seq, out, rowsum);  // xs -> out
  k_lse<<<(NN * 6 + 255) / 256, 256, 0, stream>>>(rowsum, lse);
  k_out<<<NP / 256, 256, 0, stream>>>(out, lse);
}

// Round 6
// 151.133 us; speedup vs baseline: 1.1867x; 1.0447x over previous
//
#include <hip/hip_runtime.h>

#define NN 1024
#define NP (NN * NN)
#define NBLK 1024
#define NGRP (NBLK * 16)   // 16384 groups, 2 pairs/group/iter -> 32 iters

typedef float f32x4 __attribute__((ext_vector_type(4)));

__device__ __forceinline__ f32x4 ntld(const float* p) {
  return __builtin_nontemporal_load((const f32x4*)p);
}

// DPP butterfly add within a 16-lane row, pure VALU pipe (no LDS ops):
// xor1 = quad_perm(1,0,3,2)=0xB1, xor2 = quad_perm(2,3,0,1)=0x4E,
// xor7 = row_half_mirror=0x141, xor15 = row_mirror=0x140.
// {1,2,7,15} generates the full 16-lane xor group -> all lanes get the sum.
#define DPP_ADD_STAGE(v, ctrl)                                               \
  {                                                                          \
    const int _t = __builtin_amdgcn_update_dpp(                              \
        0, __float_as_int(v), (ctrl), 0xf, 0xf, true);                       \
    (v) += __int_as_float(_t);                                               \
  }

// ---------------- k1: LayerNorm + GEMV, decoupled form, persistent grid -----
// x_d = rstd*(g_d - mu*A_d) + B_d;  A_d = sum gamma*W, B_d = sum beta*W + b.
// 16 lanes/pair, 8 ch/lane; 2 pairs per group per iter; prefetch next iter.
__global__ __launch_bounds__(256) void k_ln_gemv(
    const float* __restrict__ pairp, const float* __restrict__ gamma,
    const float* __restrict__ beta, const float* __restrict__ W,
    const float* __restrict__ bvec, float* __restrict__ xout)
{
  const int l = threadIdx.x & 15;
  const int group = blockIdx.x * 16 + (threadIdx.x >> 4);

  float ug[8][6], apart[6] = {0, 0, 0, 0, 0, 0}, bpart[6] = {0, 0, 0, 0, 0, 0};
#pragma unroll
  for (int k = 0; k < 2; ++k)
#pragma unroll
    for (int m = 0; m < 4; ++m) {
      const int c = 4 * l + 64 * k + m;
      const int idx = 4 * k + m;
      const float ga = gamma[c], be = beta[c];
#pragma unroll
      for (int d = 0; d < 6; ++d) {
        const float w = W[c * 6 + d];
        ug[idx][d] = ga * w;
        apart[d] += ga * w;
        bpart[d] += be * w;
      }
    }
#pragma unroll
  for (int d = 0; d < 6; ++d)
#pragma unroll
    for (int m = 1; m <= 8; m <<= 1) {
      apart[d] += __shfl_xor(apart[d], m);
      bpart[d] += __shfl_xor(bpart[d], m);
    }
  const float vA = (l == 0) ? apart[0] : (l == 1) ? apart[1] : (l == 2) ? apart[2]
                  : (l == 3) ? apart[3] : (l == 4) ? apart[4] : apart[5];
  float vB = (l == 0) ? bpart[0] : (l == 1) ? bpart[1] : (l == 2) ? bpart[2]
            : (l == 3) ? bpart[3] : (l == 4) ? bpart[4] : bpart[5];
  if (l < 6) vB += bvec[l];

  size_t p = 2 * (size_t)group;
  const float* bp = pairp + p * 128 + 4 * l;
  f32x4 a0 = ntld(bp), b0 = ntld(bp + 64);
  f32x4 a1 = ntld(bp + 128), b1 = ntld(bp + 192);

  for (int it = 0; it < 32; ++it) {
    const size_t pn = p + 2 * NGRP;
    f32x4 na0, nb0, na1, nb1;
    if (it != 31) {  // prefetch next iteration's 4 loads before compute
      const float* nbp = pairp + pn * 128 + 4 * l;
      na0 = ntld(nbp); nb0 = ntld(nbp + 64);
      na1 = ntld(nbp + 128); nb1 = ntld(nbp + 192);
    }

    const float xv0[8] = {a0.x, a0.y, a0.z, a0.w, b0.x, b0.y, b0.z, b0.w};
    const float xv1[8] = {a1.x, a1.y, a1.z, a1.w, b1.x, b1.y, b1.z, b1.w};
    float r[16];
#pragma unroll
    for (int k = 0; k < 16; ++k) r[k] = 0.f;
#pragma unroll
    for (int k = 0; k < 8; ++k) {
      r[0] += xv0[k];
      r[1] = fmaf(xv0[k], xv0[k], r[1]);
      r[8] += xv1[k];
      r[9] = fmaf(xv1[k], xv1[k], r[9]);
#pragma unroll
      for (int d = 0; d < 6; ++d) {
        r[2 + d] = fmaf(xv0[k], ug[k][d], r[2 + d]);
        r[10 + d] = fmaf(xv1[k], ug[k][d], r[10 + d]);
      }
    }
    // 16-lane reduction: 4 DPP stages x 16 independent values, VALU-only
#pragma unroll
    for (int k = 0; k < 16; ++k) DPP_ADD_STAGE(r[k], 0xB1);   // xor 1
#pragma unroll
    for (int k = 0; k < 16; ++k) DPP_ADD_STAGE(r[k], 0x4E);   // xor 2
#pragma unroll
    for (int k = 0; k < 16; ++k) DPP_ADD_STAGE(r[k], 0x141);  // xor 7 (half mirror)
#pragma unroll
    for (int k = 0; k < 16; ++k) DPP_ADD_STAGE(r[k], 0x140);  // xor 15 (mirror)

    if (l < 6) {
      const float mu0 = r[0] * (1.f / 128.f);
      const float var0 = r[1] * (1.f / 128.f) - mu0 * mu0;
      const float rstd0 = rsqrtf(var0 + 1e-5f);
      const float vg0 = (l == 0) ? r[2] : (l == 1) ? r[3] : (l == 2) ? r[4]
                       : (l == 3) ? r[5] : (l == 4) ? r[6] : r[7];
      xout[p * 6 + l] = fmaf(rstd0, vg0 - mu0 * vA, vB);

      const float mu1 = r[8] * (1.f / 128.f);
      const float var1 = r[9] * (1.f / 128.f) - mu1 * mu1;
      const float rstd1 = rsqrtf(var1 + 1e-5f);
      const float vg1 = (l == 0) ? r[10] : (l == 1) ? r[11] : (l == 2) ? r[12]
                       : (l == 3) ? r[13] : (l == 4) ? r[14] : r[15];
      xout[(p + 1) * 6 + l] = fmaf(rstd1, vg1 - mu1 * vA, vB);
    }
    p = pn;
    a0 = na0; b0 = nb0; a1 = na1; b1 = nb1;
  }
}

// ---------------- k_sym: one-shot tiled symmetrize + mask + rowsum -----------
__global__ __launch_bounds__(256) void k_sym(
    const float* __restrict__ x, const int* __restrict__ seq,
    float* __restrict__ xs, float* __restrict__ rowsum)
{
  const int J = blockIdx.x, I = blockIdx.y;
  const int tid = threadIdx.x;
  __shared__ float M[32 * 193];

  const float* mb = x + ((size_t)(J * 32) * NN + I * 32) * 6;
  for (int k = tid; k < 1536; k += 256) {
    const int m = k / 48, f = k % 48;
    const float4 v = *(const float4*)(mb + (size_t)m * (NN * 6) + f * 4);
    float* dst = &M[m * 193 + f * 4];
    dst[0] = v.x; dst[1] = v.y; dst[2] = v.z; dst[3] = v.w;
  }
  __syncthreads();

  float es[4][6];
#pragma unroll
  for (int q = 0; q < 4; ++q) {
    const int e = tid + 256 * q;
    const int r = e >> 5, c = e & 31;
    const int i = I * 32 + r, j = J * 32 + c;
    const int dd = seq[i] - seq[j];
    const bool far = (dd > 3) || (dd < -3);
    const float* own = x + ((size_t)i * NN + j) * 6;
    const float2 o0 = *(const float2*)(own);
    const float2 o1 = *(const float2*)(own + 2);
    const float2 o2 = *(const float2*)(own + 4);
    const float* mr = &M[c * 193 + r * 6];
    float v[6];
    v[0] = far ? 0.5f * (o0.x + mr[0]) : -1000000.f;
    v[1] = far ? 0.5f * (o0.y + mr[1]) : -1000000.f;
    v[2] = far ? 0.5f * (o1.x + mr[2]) : -1000000.f;
    v[3] = far ? 0.5f * (o1.y + mr[3]) : -1000000.f;
    v[4] = far ? 0.5f * (o2.x + mr[4]) : -1000000.f;
    v[5] = far ? 0.5f * (o2.y + mr[5]) : -1000000.f;
    float* op = xs + ((size_t)i * NN + j) * 6;
    *(float2*)(op) = make_float2(v[0], v[1]);
    *(float2*)(op + 2) = make_float2(v[2], v[3]);
    *(float2*)(op + 4) = make_float2(v[4], v[5]);
#pragma unroll
    for (int d = 0; d < 6; ++d) es[q][d] = __expf(v[d]);
  }

#pragma unroll
  for (int q = 0; q < 4; ++q)
#pragma unroll
    for (int d = 0; d < 6; ++d)
#pragma unroll
      for (int m = 1; m <= 16; m <<= 1) es[q][d] += __shfl_xor(es[q][d], m);

  if ((tid & 31) == 0) {
    const int w = tid >> 5;
#pragma unroll
    for (int q = 0; q < 4; ++q) {
      const int i = I * 32 + w + 8 * q;
#pragma unroll
      for (int d = 0; d < 6; ++d) atomicAdd(&rowsum[i * 6 + d], es[q][d]);
    }
  }
}

__global__ __launch_bounds__(256) void k_lse(
    const float* __restrict__ rowsum, float* __restrict__ lse)
{
  const int k = blockIdx.x * 256 + threadIdx.x;
  if (k < NN * 6) lse[k] = logf(1.0f + rowsum[k]);
}

__global__ __launch_bounds__(256) void k_out(
    float* __restrict__ out, const float* __restrict__ lse)
{
  const int p = blockIdx.x * 256 + threadIdx.x;
  const int i = p >> 10;
  const int j = p & (NN - 1);

  float* a = out + (size_t)p * 6;
  const float2 a0 = *(const float2*)(a);
  const float2 a1 = *(const float2*)(a + 2);
  const float2 a2 = *(const float2*)(a + 4);
  const float v[6] = {a0.x, a0.y, a1.x, a1.y, a2.x, a2.y};

  float ssum = 0.f;
#pragma unroll
  for (int d = 0; d < 6; ++d) ssum += __expf(v[d]);
  const float lc2 = 2.f * logf(1.f + ssum);

  const float* li = lse + i * 6;
  const float* lj = lse + j * 6;
  float o[6];
#pragma unroll
  for (int d = 0; d < 6; ++d) o[d] = 4.f * v[d] - li[d] - lj[d] - lc2;

  *(float2*)(a) = make_float2(o[0], o[1]);
  *(float2*)(a + 2) = make_float2(o[2], o[3]);
  *(float2*)(a + 4) = make_float2(o[4], o[5]);
}

extern "C" void kernel_launch(void* const* d_in, const int* in_sizes, int n_in,
                              void* d_out, int out_size, void* d_ws, size_t ws_size,
                              hipStream_t stream) {
  const float* pairp = (const float*)d_in[0];
  const int* seq = (const int*)d_in[1];
  const float* gamma = (const float*)d_in[2];
  const float* beta = (const float*)d_in[3];
  const float* W = (const float*)d_in[4];
  const float* bvec = (const float*)d_in[5];
  float* out = (float*)d_out;

  float* x = (float*)d_ws;              // raw x: 1024*1024*6 fp32 = 24 MB
  float* rowsum = x + (size_t)NP * 6;   // 1024*6
  float* lse = rowsum + NN * 6;         // 1024*6

  hipMemsetAsync(rowsum, 0, NN * 6 * sizeof(float), stream);
  k_ln_gemv<<<NBLK, 256, 0, stream>>>(pairp, gamma, beta, W, bvec, x);
  k_sym<<<dim3(32, 32), 256, 0, stream>>>(x, seq, out, rowsum);  // xs -> out
  k_lse<<<(NN * 6 + 255) / 256, 256, 0, stream>>>(rowsum, lse);
  k_out<<<NP / 256, 256, 0, stream>>>(out, lse);
}